// Round 5
// baseline (214.952 us; speedup 1.0000x reference)
//
#include <hip/hip_runtime.h>

typedef _Float16 half8 __attribute__((ext_vector_type(8)));
typedef float f32x4 __attribute__((ext_vector_type(4)));
typedef unsigned short u16;

#define NHEAD 12
#define DHEAD 64
#define DM    768
#define TSEQ  1024
#define LOG2E 1.44269504f

// ws layout (fp16 elements unless noted). ctx aliases xh (xh dead after qkv).
static constexpr size_t OFF_XH  = 0;         // [4096][768]
static constexpr size_t OFF_WQH = 3145728;   // [768][768]
static constexpr size_t OFF_WKH = 3735552;
static constexpr size_t OFF_WVH = 4325376;
static constexpr size_t OFF_WOH = 4915200;
static constexpr size_t OFF_Q   = 5505024;   // [48][1024][64]
static constexpr size_t OFF_K   = 8650752;   // [48][1024][64]
static constexpr size_t OFF_VT  = 11796480;  // [48][64][1024]
static constexpr size_t OFF_CTX = 0;         // [4096][768], aliases XH
// split-K extras:
static constexpr size_t OFF_OP  = 14942208;  // O partials [2][48*1024][64] fp16
static constexpr size_t OFF_ML_BYTES = 42467328;  // (OFF_OP+6291456)*2; [2][48*1024][2] f32
static constexpr size_t WS_NEED_SPLITK = 43253760; // bytes

typedef const __attribute__((address_space(1))) void* gas_ptr;
typedef __attribute__((address_space(3))) void* las_ptr;
__device__ __forceinline__ void gload16(const _Float16* g, _Float16* l) {
    __builtin_amdgcn_global_load_lds((gas_ptr)g, (las_ptr)l, 16, 0, 0);
}

// ---------------- fp32 -> fp16 conversion of x + 4 weights ----------------
__global__ void cvt_kernel(const float* __restrict__ x, const float* __restrict__ wq,
                           const float* __restrict__ wk, const float* __restrict__ wv,
                           const float* __restrict__ wo, _Float16* __restrict__ ws) {
    int seg = blockIdx.y;
    const float* src;
    _Float16* dst;
    int n;
    if (seg == 0)      { src = x;  dst = ws + OFF_XH;  n = 3145728; }
    else if (seg == 1) { src = wq; dst = ws + OFF_WQH; n = 589824; }
    else if (seg == 2) { src = wk; dst = ws + OFF_WKH; n = 589824; }
    else if (seg == 3) { src = wv; dst = ws + OFF_WVH; n = 589824; }
    else               { src = wo; dst = ws + OFF_WOH; n = 589824; }
    int i = (blockIdx.x * blockDim.x + threadIdx.x) * 8;
    if (i < n) {
        float4 v0 = *(const float4*)(src + i);
        float4 v1 = *(const float4*)(src + i + 4);
        half8 o;
        o[0] = (_Float16)v0.x; o[1] = (_Float16)v0.y;
        o[2] = (_Float16)v0.z; o[3] = (_Float16)v0.w;
        o[4] = (_Float16)v1.x; o[5] = (_Float16)v1.y;
        o[6] = (_Float16)v1.z; o[7] = (_Float16)v1.w;
        *(half8*)(dst + i) = o;
    }
}

// ---------------- QKV GEMM, m97-style LDS-staged ----------------
__global__ __launch_bounds__(256) void qkv_kernel(_Float16* __restrict__ ws) {
    __shared__ __align__(16) _Float16 ldsA[128 * 32];
    __shared__ __align__(16) _Float16 ldsB[128 * 32];

    const int z = blockIdx.z;
    const _Float16* __restrict__ xh = ws + OFF_XH;
    const _Float16* __restrict__ w  = ws + (z == 0 ? OFF_WQH : z == 1 ? OFF_WKH : OFF_WVH);
    _Float16* __restrict__ outp     = ws + (z == 0 ? OFF_Q   : z == 1 ? OFF_K   : OFF_VT);

    const int tid  = threadIdx.x;
    const int lane = tid & 63;
    const int wid  = tid >> 6;
    const int quad = lane >> 4, l15 = lane & 15;
    const int wm = (wid & 1) * 64, wn = (wid >> 1) * 64;

    int mb, nb;
    const _Float16 *gA, *gB;
    if (z < 2) {
        mb = blockIdx.x * 128;              // tokens
        nb = blockIdx.y * 128;              // features
        gA = xh + (size_t)mb * DM;
        gB = w  + (size_t)nb * DM;
    } else {
        mb = blockIdx.y * 128;              // features
        nb = blockIdx.x * 128;              // tokens
        gA = w  + (size_t)mb * DM;
        gB = xh + (size_t)nb * DM;
    }

    const int srow = (lane >> 2);
    const int scol = (lane & 3) * 8;
    const size_t goff0 = (size_t)(wid * 32 + srow) * DM + scol;
    const size_t goff1 = (size_t)(wid * 32 + 16 + srow) * DM + scol;
    _Float16* lA0 = ldsA + wid * 1024;
    _Float16* lA1 = ldsA + wid * 1024 + 512;
    _Float16* lB0 = ldsB + wid * 1024;
    _Float16* lB1 = ldsB + wid * 1024 + 512;

    f32x4 acc[4][4] = {};
    for (int k0 = 0; k0 < DM; k0 += 32) {
        gload16(gA + goff0 + k0, lA0);
        gload16(gA + goff1 + k0, lA1);
        gload16(gB + goff0 + k0, lB0);
        gload16(gB + goff1 + k0, lB1);
        __syncthreads();

        half8 a[4], b[4];
#pragma unroll
        for (int t = 0; t < 4; t++) {
            a[t] = *(const half8*)(ldsA + (wm + t * 16 + l15) * 32 + quad * 8);
            b[t] = *(const half8*)(ldsB + (wn + t * 16 + l15) * 32 + quad * 8);
        }
#pragma unroll
        for (int mt = 0; mt < 4; mt++)
#pragma unroll
            for (int nt = 0; nt < 4; nt++)
                acc[mt][nt] = __builtin_amdgcn_mfma_f32_16x16x32_f16(a[mt], b[nt], acc[mt][nt], 0, 0, 0);
        __syncthreads();
    }

#pragma unroll
    for (int mt = 0; mt < 4; mt++)
#pragma unroll
        for (int nt = 0; nt < 4; nt++)
#pragma unroll
            for (int r = 0; r < 4; r++) {
                int m = mb + wm + mt * 16 + quad * 4 + r;
                int n = nb + wn + nt * 16 + l15;
                size_t idx;
                if (z < 2) {
                    int bb = m >> 10, tt = m & 1023;
                    int h = n >> 6, d = n & 63;
                    idx = ((size_t)(bb * NHEAD + h) * TSEQ + tt) * DHEAD + d;
                } else {
                    int h = m >> 6, d = m & 63;
                    int bb = n >> 10, tt = n & 1023;
                    idx = ((size_t)(bb * NHEAD + h) * DHEAD + d) * TSEQ + tt;
                }
                outp[idx] = (_Float16)acc[mt][nt][r];
            }
}

// ---------------- flash attention core (templated over split) ----------------
// grid (16, 48, NZ); block 256 = 4 waves; wave q-tile 16; key tiles of 64.
template <int NZ>
__device__ __forceinline__ void attn_body(_Float16* __restrict__ ws) {
    __shared__ __align__(16) _Float16 ldsK[64 * 64];
    __shared__ __align__(16) _Float16 ldsV[64 * 64];
    __shared__ __align__(16) _Float16 ldsP[4][16 * 72];

    const int tid  = threadIdx.x;
    const int lane = tid & 63;
    const int wid  = tid >> 6;
    const int quad = lane >> 4, l15 = lane & 15;
    const int bh = blockIdx.y;
    const int z  = (NZ > 1) ? blockIdx.z : 0;
    const int q0 = blockIdx.x * 64 + wid * 16;
    const int kbeg = z * (TSEQ / NZ), kend = kbeg + TSEQ / NZ;

    const _Float16* __restrict__ Q  = ws + OFF_Q  + (size_t)bh * TSEQ * DHEAD;
    const _Float16* __restrict__ K  = ws + OFF_K  + (size_t)bh * TSEQ * DHEAD;
    const _Float16* __restrict__ VT = ws + OFF_VT + (size_t)bh * DHEAD * TSEQ;
    _Float16* pbase = ldsP[wid];

    const int srow0 = tid >> 3, sc0 = tid & 7;
    const int ldsOff0 = srow0 * 64 + ((sc0 ^ (srow0 & 7)) * 8);
    const int ldsOff1 = (srow0 + 32) * 64 + ((sc0 ^ (srow0 & 7)) * 8);

    half8 qf[2];
#pragma unroll
    for (int ks = 0; ks < 2; ks++) {
        qf[ks] = *(const half8*)(Q + (size_t)(q0 + l15) * DHEAD + ks * 32 + quad * 8);
        qf[ks] = qf[ks] * (_Float16)0.125f;   // fold 1/sqrt(64) into Q
    }

    float mrun[4], lrun[4];
    f32x4 oacc[4] = {};
#pragma unroll
    for (int r = 0; r < 4; r++) { mrun[r] = -1e30f; lrun[r] = 0.f; }

    uint4 ka, kb, va, vb;
    ka = *(const uint4*)(K + kbeg * DHEAD + tid * 8);
    kb = *(const uint4*)(K + kbeg * DHEAD + 2048 + tid * 8);
    va = *(const uint4*)(VT + (size_t)srow0 * TSEQ + kbeg + sc0 * 8);
    vb = *(const uint4*)(VT + (size_t)(srow0 + 32) * TSEQ + kbeg + sc0 * 8);

    for (int kt = kbeg; kt < kend; kt += 64) {
        *(uint4*)(ldsK + ldsOff0) = ka;
        *(uint4*)(ldsK + ldsOff1) = kb;
        *(uint4*)(ldsV + ldsOff0) = va;
        *(uint4*)(ldsV + ldsOff1) = vb;
        __syncthreads();

        if (kt + 64 < kend) {
            ka = *(const uint4*)(K + (kt + 64) * DHEAD + tid * 8);
            kb = *(const uint4*)(K + (kt + 64) * DHEAD + 2048 + tid * 8);
            va = *(const uint4*)(VT + (size_t)srow0 * TSEQ + kt + 64 + sc0 * 8);
            vb = *(const uint4*)(VT + (size_t)(srow0 + 32) * TSEQ + kt + 64 + sc0 * 8);
        }

        half8 kf[4][2];
#pragma unroll
        for (int n = 0; n < 4; n++)
#pragma unroll
            for (int ks = 0; ks < 2; ks++) {
                int row = n * 16 + l15;
                int phys = (ks * 4 + quad) ^ (row & 7);
                kf[n][ks] = *(const half8*)(ldsK + row * 64 + phys * 8);
            }

        f32x4 s[4] = {};
#pragma unroll
        for (int n = 0; n < 4; n++)
#pragma unroll
            for (int ks = 0; ks < 2; ks++)
                s[n] = __builtin_amdgcn_mfma_f32_16x16x32_f16(qf[ks], kf[n][ks], s[n], 0, 0, 0);

#pragma unroll
        for (int r = 0; r < 4; r++) {
            float tm = fmaxf(fmaxf(s[0][r], s[1][r]), fmaxf(s[2][r], s[3][r]));
#pragma unroll
            for (int off = 1; off < 16; off <<= 1) tm = fmaxf(tm, __shfl_xor(tm, off, 64));
            float mnew = fmaxf(mrun[r], tm);
            float alpha = __builtin_amdgcn_exp2f((mrun[r] - mnew) * LOG2E);
            mrun[r] = mnew;
            float mL = mnew * LOG2E;
            float ts = 0.f;
#pragma unroll
            for (int n = 0; n < 4; n++) {
                float e = __builtin_amdgcn_exp2f(__builtin_fmaf(s[n][r], LOG2E, -mL));
                s[n][r] = e;
                ts += e;
            }
#pragma unroll
            for (int off = 1; off < 16; off <<= 1) ts += __shfl_xor(ts, off, 64);
            lrun[r] = __builtin_fmaf(lrun[r], alpha, ts);
#pragma unroll
            for (int dn = 0; dn < 4; dn++) oacc[dn][r] *= alpha;
        }

#pragma unroll
        for (int n = 0; n < 4; n++)
#pragma unroll
            for (int r = 0; r < 4; r++)
                pbase[(quad * 4 + r) * 72 + n * 16 + l15] = (_Float16)s[n][r];

        half8 vf[4][2];
#pragma unroll
        for (int dn = 0; dn < 4; dn++)
#pragma unroll
            for (int ks = 0; ks < 2; ks++) {
                int row = dn * 16 + l15;
                int phys = (ks * 4 + quad) ^ (row & 7);
                vf[dn][ks] = *(const half8*)(ldsV + row * 64 + phys * 8);
            }

        half8 pf[2];
#pragma unroll
        for (int ks = 0; ks < 2; ks++)
            pf[ks] = *(const half8*)(pbase + l15 * 72 + ks * 32 + quad * 8);

#pragma unroll
        for (int dn = 0; dn < 4; dn++)
#pragma unroll
            for (int ks = 0; ks < 2; ks++)
                oacc[dn] = __builtin_amdgcn_mfma_f32_16x16x32_f16(pf[ks], vf[dn][ks], oacc[dn], 0, 0, 0);

        __syncthreads();
    }

    if (NZ == 1) {
        // direct epilogue: O / l -> ctx (fp16)
        _Float16* __restrict__ ctx = ws + OFF_CTX;
        const int b_ = bh / NHEAD, h = bh % NHEAD;
#pragma unroll
        for (int dn = 0; dn < 4; dn++)
#pragma unroll
            for (int r = 0; r < 4; r++) {
                int t_ = q0 + quad * 4 + r;
                int col = h * DHEAD + dn * 16 + l15;
                float v = oacc[dn][r] / lrun[r];
                ctx[((size_t)(b_ * TSEQ + t_)) * DM + col] = (_Float16)v;
            }
    } else {
        // partial epilogue: unnormalized O (fp16) + (m,l) f32
        _Float16* __restrict__ op = ws + OFF_OP;
        float* __restrict__ ml = (float*)((char*)ws + OFF_ML_BYTES);
        const size_t rowbase = (size_t)z * 48 * TSEQ + (size_t)bh * TSEQ + q0;
#pragma unroll
        for (int dn = 0; dn < 4; dn++)
#pragma unroll
            for (int r = 0; r < 4; r++) {
                size_t row = rowbase + quad * 4 + r;
                op[row * 64 + dn * 16 + l15] = (_Float16)oacc[dn][r];
            }
        if (l15 == 0) {
#pragma unroll
            for (int r = 0; r < 4; r++) {
                size_t row = rowbase + quad * 4 + r;
                ml[row * 2]     = mrun[r];
                ml[row * 2 + 1] = lrun[r];
            }
        }
    }
}

__global__ __launch_bounds__(256, 3) void attn_kernel(_Float16* __restrict__ ws) {
    attn_body<1>(ws);
}
__global__ __launch_bounds__(256, 6) void attn_splitk_kernel(_Float16* __restrict__ ws) {
    attn_body<2>(ws);
}

// ---------------- split-K combine: merge 2 partials -> ctx fp16 ----------------
__global__ __launch_bounds__(256) void combine_kernel(_Float16* __restrict__ ws) {
    const _Float16* __restrict__ op = ws + OFF_OP;
    const float* __restrict__ ml = (const float*)((const char*)ws + OFF_ML_BYTES);
    _Float16* __restrict__ ctx = ws + OFF_CTX;

    int g = blockIdx.x * 256 + threadIdx.x;     // 393216 threads
    int row = g >> 3, chunk = g & 7;            // row in [0, 49152)
    int bh = row >> 10, q = row & 1023;
    int b_ = bh / NHEAD, h = bh % NHEAD;

    float m0 = ml[(size_t)row * 2], l0 = ml[(size_t)row * 2 + 1];
    float m1 = ml[(size_t)(49152 + row) * 2], l1 = ml[(size_t)(49152 + row) * 2 + 1];
    float M = fmaxf(m0, m1);
    float w0 = __builtin_amdgcn_exp2f((m0 - M) * LOG2E);
    float w1 = __builtin_amdgcn_exp2f((m1 - M) * LOG2E);
    float inv_l = 1.0f / (w0 * l0 + w1 * l1);

    half8 o0 = *(const half8*)(op + (size_t)row * 64 + chunk * 8);
    half8 o1 = *(const half8*)(op + (size_t)(49152 + row) * 64 + chunk * 8);
    half8 o;
#pragma unroll
    for (int j = 0; j < 8; j++)
        o[j] = (_Float16)(((float)o0[j] * w0 + (float)o1[j] * w1) * inv_l);
    *(half8*)(ctx + ((size_t)(b_ * TSEQ + q)) * DM + h * DHEAD + chunk * 8) = o;
}

// ---------------- output projection, m97-style: out = ctx @ Wo^T + bo (fp32) ----------------
__global__ __launch_bounds__(256) void proj_kernel(const _Float16* __restrict__ ws,
                                                   const float* __restrict__ bo,
                                                   float* __restrict__ out) {
    __shared__ __align__(16) _Float16 ldsA[128 * 32];
    __shared__ __align__(16) _Float16 ldsB[128 * 32];

    const _Float16* __restrict__ gA = ws + OFF_CTX + (size_t)blockIdx.x * 128 * DM;
    const _Float16* __restrict__ gB = ws + OFF_WOH + (size_t)blockIdx.y * 128 * DM;

    const int tid  = threadIdx.x;
    const int lane = tid & 63;
    const int wid  = tid >> 6;
    const int quad = lane >> 4, l15 = lane & 15;
    const int wm = (wid & 1) * 64, wn = (wid >> 1) * 64;

    const int srow = (lane >> 2);
    const int scol = (lane & 3) * 8;
    const size_t goff0 = (size_t)(wid * 32 + srow) * DM + scol;
    const size_t goff1 = (size_t)(wid * 32 + 16 + srow) * DM + scol;
    _Float16* lA0 = ldsA + wid * 1024;
    _Float16* lA1 = ldsA + wid * 1024 + 512;
    _Float16* lB0 = ldsB + wid * 1024;
    _Float16* lB1 = ldsB + wid * 1024 + 512;

    f32x4 acc[4][4] = {};
    for (int k0 = 0; k0 < DM; k0 += 32) {
        gload16(gA + goff0 + k0, lA0);
        gload16(gA + goff1 + k0, lA1);
        gload16(gB + goff0 + k0, lB0);
        gload16(gB + goff1 + k0, lB1);
        __syncthreads();

        half8 a[4], b[4];
#pragma unroll
        for (int t = 0; t < 4; t++) {
            a[t] = *(const half8*)(ldsA + (wm + t * 16 + l15) * 32 + quad * 8);
            b[t] = *(const half8*)(ldsB + (wn + t * 16 + l15) * 32 + quad * 8);
        }
#pragma unroll
        for (int mt = 0; mt < 4; mt++)
#pragma unroll
            for (int nt = 0; nt < 4; nt++)
                acc[mt][nt] = __builtin_amdgcn_mfma_f32_16x16x32_f16(a[mt], b[nt], acc[mt][nt], 0, 0, 0);
        __syncthreads();
    }

    const int mb = blockIdx.x * 128, nb = blockIdx.y * 128;
#pragma unroll
    for (int mt = 0; mt < 4; mt++)
#pragma unroll
        for (int nt = 0; nt < 4; nt++)
#pragma unroll
            for (int r = 0; r < 4; r++) {
                int m = mb + wm + mt * 16 + quad * 4 + r;
                int n = nb + wn + nt * 16 + l15;
                out[(size_t)m * DM + n] = acc[mt][nt][r] + bo[n];
            }
}

extern "C" void kernel_launch(void* const* d_in, const int* in_sizes, int n_in,
                              void* d_out, int out_size, void* d_ws, size_t ws_size,
                              hipStream_t stream) {
    const float* x  = (const float*)d_in[0];
    const float* wq = (const float*)d_in[1];
    const float* wk = (const float*)d_in[2];
    const float* wv = (const float*)d_in[3];
    const float* wo = (const float*)d_in[4];
    const float* bo = (const float*)d_in[5];
    _Float16* ws = (_Float16*)d_ws;
    float* out = (float*)d_out;

    cvt_kernel<<<dim3(1536, 5, 1), 256, 0, stream>>>(x, wq, wk, wv, wo, ws);
    qkv_kernel<<<dim3(32, 6, 3), 256, 0, stream>>>(ws);
    if (ws_size >= WS_NEED_SPLITK) {
        attn_splitk_kernel<<<dim3(16, 48, 2), 256, 0, stream>>>(ws);
        combine_kernel<<<dim3(1536, 1, 1), 256, 0, stream>>>(ws);
    } else {
        attn_kernel<<<dim3(16, 48, 1), 256, 0, stream>>>(ws);
    }
    proj_kernel<<<dim3(32, 6, 1), 256, 0, stream>>>(ws, bo, out);
}

// Round 6
// 162.205 us; speedup vs baseline: 1.3252x; 1.3252x over previous
//
#include <hip/hip_runtime.h>

typedef _Float16 half8 __attribute__((ext_vector_type(8)));
typedef float f32x4 __attribute__((ext_vector_type(4)));
typedef unsigned short u16;

#define NHEAD 12
#define DHEAD 64
#define DM    768
#define TSEQ  1024
#define LOG2E 1.44269504f

// ws layout (fp16 elements unless noted). ctx aliases xh (xh dead after qkv).
static constexpr size_t OFF_XH  = 0;         // [4096][768]
static constexpr size_t OFF_WQH = 3145728;   // [768][768]
static constexpr size_t OFF_WKH = 3735552;
static constexpr size_t OFF_WVH = 4325376;
static constexpr size_t OFF_WOH = 4915200;
static constexpr size_t OFF_Q   = 5505024;   // [48][1024][64]
static constexpr size_t OFF_K   = 8650752;   // [48][1024][64]
static constexpr size_t OFF_VT  = 11796480;  // [48][64][1024]
static constexpr size_t OFF_CTX = 0;         // [4096][768], aliases XH
// split-K extras:
static constexpr size_t OFF_OP  = 14942208;  // O partials [2][48*1024][64] fp16
static constexpr size_t OFF_ML_BYTES = 42467328;  // [2][48*1024][2] f32
static constexpr size_t WS_NEED_SPLITK = 43253760; // bytes

typedef const __attribute__((address_space(1))) void* gas_ptr;
typedef __attribute__((address_space(3))) void* las_ptr;
__device__ __forceinline__ void gload16(const _Float16* g, _Float16* l) {
    __builtin_amdgcn_global_load_lds((gas_ptr)g, (las_ptr)l, 16, 0, 0);
}

// ---------------- fp32 -> fp16 conversion of x + 4 weights ----------------
__global__ void cvt_kernel(const float* __restrict__ x, const float* __restrict__ wq,
                           const float* __restrict__ wk, const float* __restrict__ wv,
                           const float* __restrict__ wo, _Float16* __restrict__ ws) {
    int seg = blockIdx.y;
    const float* src;
    _Float16* dst;
    int n;
    if (seg == 0)      { src = x;  dst = ws + OFF_XH;  n = 3145728; }
    else if (seg == 1) { src = wq; dst = ws + OFF_WQH; n = 589824; }
    else if (seg == 2) { src = wk; dst = ws + OFF_WKH; n = 589824; }
    else if (seg == 3) { src = wv; dst = ws + OFF_WVH; n = 589824; }
    else               { src = wo; dst = ws + OFF_WOH; n = 589824; }
    int i = (blockIdx.x * blockDim.x + threadIdx.x) * 8;
    if (i < n) {
        float4 v0 = *(const float4*)(src + i);
        float4 v1 = *(const float4*)(src + i + 4);
        half8 o;
        o[0] = (_Float16)v0.x; o[1] = (_Float16)v0.y;
        o[2] = (_Float16)v0.z; o[3] = (_Float16)v0.w;
        o[4] = (_Float16)v1.x; o[5] = (_Float16)v1.y;
        o[6] = (_Float16)v1.z; o[7] = (_Float16)v1.w;
        *(half8*)(dst + i) = o;
    }
}

// ---------------- QKV GEMM, m97-style LDS-staged ----------------
__global__ __launch_bounds__(256) void qkv_kernel(_Float16* __restrict__ ws) {
    __shared__ __align__(16) _Float16 ldsA[128 * 32];
    __shared__ __align__(16) _Float16 ldsB[128 * 32];

    const int z = blockIdx.z;
    const _Float16* __restrict__ xh = ws + OFF_XH;
    const _Float16* __restrict__ w  = ws + (z == 0 ? OFF_WQH : z == 1 ? OFF_WKH : OFF_WVH);
    _Float16* __restrict__ outp     = ws + (z == 0 ? OFF_Q   : z == 1 ? OFF_K   : OFF_VT);

    const int tid  = threadIdx.x;
    const int lane = tid & 63;
    const int wid  = tid >> 6;
    const int quad = lane >> 4, l15 = lane & 15;
    const int wm = (wid & 1) * 64, wn = (wid >> 1) * 64;

    int mb, nb;
    const _Float16 *gA, *gB;
    if (z < 2) {
        mb = blockIdx.x * 128;              // tokens
        nb = blockIdx.y * 128;              // features
        gA = xh + (size_t)mb * DM;
        gB = w  + (size_t)nb * DM;
    } else {
        mb = blockIdx.y * 128;              // features
        nb = blockIdx.x * 128;              // tokens
        gA = w  + (size_t)mb * DM;
        gB = xh + (size_t)nb * DM;
    }

    const int srow = (lane >> 2);
    const int scol = (lane & 3) * 8;
    const size_t goff0 = (size_t)(wid * 32 + srow) * DM + scol;
    const size_t goff1 = (size_t)(wid * 32 + 16 + srow) * DM + scol;
    _Float16* lA0 = ldsA + wid * 1024;
    _Float16* lA1 = ldsA + wid * 1024 + 512;
    _Float16* lB0 = ldsB + wid * 1024;
    _Float16* lB1 = ldsB + wid * 1024 + 512;

    f32x4 acc[4][4] = {};
    for (int k0 = 0; k0 < DM; k0 += 32) {
        gload16(gA + goff0 + k0, lA0);
        gload16(gA + goff1 + k0, lA1);
        gload16(gB + goff0 + k0, lB0);
        gload16(gB + goff1 + k0, lB1);
        __syncthreads();

        half8 a[4], b[4];
#pragma unroll
        for (int t = 0; t < 4; t++) {
            a[t] = *(const half8*)(ldsA + (wm + t * 16 + l15) * 32 + quad * 8);
            b[t] = *(const half8*)(ldsB + (wn + t * 16 + l15) * 32 + quad * 8);
        }
#pragma unroll
        for (int mt = 0; mt < 4; mt++)
#pragma unroll
            for (int nt = 0; nt < 4; nt++)
                acc[mt][nt] = __builtin_amdgcn_mfma_f32_16x16x32_f16(a[mt], b[nt], acc[mt][nt], 0, 0, 0);
        __syncthreads();
    }

#pragma unroll
    for (int mt = 0; mt < 4; mt++)
#pragma unroll
        for (int nt = 0; nt < 4; nt++)
#pragma unroll
            for (int r = 0; r < 4; r++) {
                int m = mb + wm + mt * 16 + quad * 4 + r;
                int n = nb + wn + nt * 16 + l15;
                size_t idx;
                if (z < 2) {
                    int bb = m >> 10, tt = m & 1023;
                    int h = n >> 6, d = n & 63;
                    idx = ((size_t)(bb * NHEAD + h) * TSEQ + tt) * DHEAD + d;
                } else {
                    int h = m >> 6, d = m & 63;
                    int bb = n >> 10, tt = n & 1023;
                    idx = ((size_t)(bb * NHEAD + h) * DHEAD + d) * TSEQ + tt;
                }
                outp[idx] = (_Float16)acc[mt][nt][r];
            }
}

// ---------------- flash attention core (templated over split) ----------------
// grid (16, 48, NZ); block 256 = 4 waves; wave q-tile 16; key tiles of 64.
template <int NZ>
__device__ __forceinline__ void attn_body(_Float16* __restrict__ ws) {
    __shared__ __align__(16) _Float16 ldsK[64 * 64];
    __shared__ __align__(16) _Float16 ldsV[64 * 64];
    __shared__ __align__(16) _Float16 ldsP[4][16 * 72];

    const int tid  = threadIdx.x;
    const int lane = tid & 63;
    const int wid  = tid >> 6;
    const int quad = lane >> 4, l15 = lane & 15;
    const int bh = blockIdx.y;
    const int z  = (NZ > 1) ? blockIdx.z : 0;
    const int q0 = blockIdx.x * 64 + wid * 16;
    const int kbeg = z * (TSEQ / NZ), kend = kbeg + TSEQ / NZ;

    const _Float16* __restrict__ Q  = ws + OFF_Q  + (size_t)bh * TSEQ * DHEAD;
    const _Float16* __restrict__ K  = ws + OFF_K  + (size_t)bh * TSEQ * DHEAD;
    const _Float16* __restrict__ VT = ws + OFF_VT + (size_t)bh * DHEAD * TSEQ;
    _Float16* pbase = ldsP[wid];

    const int srow0 = tid >> 3, sc0 = tid & 7;
    const int ldsOff0 = srow0 * 64 + ((sc0 ^ (srow0 & 7)) * 8);
    const int ldsOff1 = (srow0 + 32) * 64 + ((sc0 ^ (srow0 & 7)) * 8);

    half8 qf[2];
#pragma unroll
    for (int ks = 0; ks < 2; ks++) {
        qf[ks] = *(const half8*)(Q + (size_t)(q0 + l15) * DHEAD + ks * 32 + quad * 8);
        qf[ks] = qf[ks] * (_Float16)0.125f;   // fold 1/sqrt(64) into Q
    }

    float mrun[4], lrun[4];
    f32x4 oacc[4] = {};
#pragma unroll
    for (int r = 0; r < 4; r++) { mrun[r] = -1e30f; lrun[r] = 0.f; }

    uint4 ka, kb, va, vb;
    ka = *(const uint4*)(K + kbeg * DHEAD + tid * 8);
    kb = *(const uint4*)(K + kbeg * DHEAD + 2048 + tid * 8);
    va = *(const uint4*)(VT + (size_t)srow0 * TSEQ + kbeg + sc0 * 8);
    vb = *(const uint4*)(VT + (size_t)(srow0 + 32) * TSEQ + kbeg + sc0 * 8);

    for (int kt = kbeg; kt < kend; kt += 64) {
        *(uint4*)(ldsK + ldsOff0) = ka;
        *(uint4*)(ldsK + ldsOff1) = kb;
        *(uint4*)(ldsV + ldsOff0) = va;
        *(uint4*)(ldsV + ldsOff1) = vb;
        __syncthreads();

        if (kt + 64 < kend) {
            ka = *(const uint4*)(K + (kt + 64) * DHEAD + tid * 8);
            kb = *(const uint4*)(K + (kt + 64) * DHEAD + 2048 + tid * 8);
            va = *(const uint4*)(VT + (size_t)srow0 * TSEQ + kt + 64 + sc0 * 8);
            vb = *(const uint4*)(VT + (size_t)(srow0 + 32) * TSEQ + kt + 64 + sc0 * 8);
        }

        half8 kf[4][2];
#pragma unroll
        for (int n = 0; n < 4; n++)
#pragma unroll
            for (int ks = 0; ks < 2; ks++) {
                int row = n * 16 + l15;
                int phys = (ks * 4 + quad) ^ (row & 7);
                kf[n][ks] = *(const half8*)(ldsK + row * 64 + phys * 8);
            }

        f32x4 s[4] = {};
#pragma unroll
        for (int n = 0; n < 4; n++)
#pragma unroll
            for (int ks = 0; ks < 2; ks++)
                s[n] = __builtin_amdgcn_mfma_f32_16x16x32_f16(qf[ks], kf[n][ks], s[n], 0, 0, 0);

#pragma unroll
        for (int r = 0; r < 4; r++) {
            float tm = fmaxf(fmaxf(s[0][r], s[1][r]), fmaxf(s[2][r], s[3][r]));
#pragma unroll
            for (int off = 1; off < 16; off <<= 1) tm = fmaxf(tm, __shfl_xor(tm, off, 64));
            float mnew = fmaxf(mrun[r], tm);
            float alpha = __builtin_amdgcn_exp2f((mrun[r] - mnew) * LOG2E);
            mrun[r] = mnew;
            float mL = mnew * LOG2E;
            float ts = 0.f;
#pragma unroll
            for (int n = 0; n < 4; n++) {
                float e = __builtin_amdgcn_exp2f(__builtin_fmaf(s[n][r], LOG2E, -mL));
                s[n][r] = e;
                ts += e;
            }
#pragma unroll
            for (int off = 1; off < 16; off <<= 1) ts += __shfl_xor(ts, off, 64);
            lrun[r] = __builtin_fmaf(lrun[r], alpha, ts);
#pragma unroll
            for (int dn = 0; dn < 4; dn++) oacc[dn][r] *= alpha;
        }

#pragma unroll
        for (int n = 0; n < 4; n++)
#pragma unroll
            for (int r = 0; r < 4; r++)
                pbase[(quad * 4 + r) * 72 + n * 16 + l15] = (_Float16)s[n][r];

        half8 vf[4][2];
#pragma unroll
        for (int dn = 0; dn < 4; dn++)
#pragma unroll
            for (int ks = 0; ks < 2; ks++) {
                int row = dn * 16 + l15;
                int phys = (ks * 4 + quad) ^ (row & 7);
                vf[dn][ks] = *(const half8*)(ldsV + row * 64 + phys * 8);
            }

        half8 pf[2];
#pragma unroll
        for (int ks = 0; ks < 2; ks++)
            pf[ks] = *(const half8*)(pbase + l15 * 72 + ks * 32 + quad * 8);

#pragma unroll
        for (int dn = 0; dn < 4; dn++)
#pragma unroll
            for (int ks = 0; ks < 2; ks++)
                oacc[dn] = __builtin_amdgcn_mfma_f32_16x16x32_f16(pf[ks], vf[dn][ks], oacc[dn], 0, 0, 0);

        __syncthreads();
    }

    if (NZ == 1) {
        _Float16* __restrict__ ctx = ws + OFF_CTX;
        const int b_ = bh / NHEAD, h = bh % NHEAD;
#pragma unroll
        for (int dn = 0; dn < 4; dn++)
#pragma unroll
            for (int r = 0; r < 4; r++) {
                int t_ = q0 + quad * 4 + r;
                int col = h * DHEAD + dn * 16 + l15;
                float v = oacc[dn][r] / lrun[r];
                ctx[((size_t)(b_ * TSEQ + t_)) * DM + col] = (_Float16)v;
            }
    } else {
        _Float16* __restrict__ op = ws + OFF_OP;
        float* __restrict__ ml = (float*)((char*)ws + OFF_ML_BYTES);
        const size_t rowbase = (size_t)z * 48 * TSEQ + (size_t)bh * TSEQ + q0;
#pragma unroll
        for (int dn = 0; dn < 4; dn++)
#pragma unroll
            for (int r = 0; r < 4; r++) {
                size_t row = rowbase + quad * 4 + r;
                op[row * 64 + dn * 16 + l15] = (_Float16)oacc[dn][r];
            }
        if (l15 == 0) {
#pragma unroll
            for (int r = 0; r < 4; r++) {
                size_t row = rowbase + quad * 4 + r;
                ml[row * 2]     = mrun[r];
                ml[row * 2 + 1] = lrun[r];
            }
        }
    }
}

__global__ __launch_bounds__(256, 3) void attn_kernel(_Float16* __restrict__ ws) {
    attn_body<1>(ws);
}
// (256,4): VGPR cap 128 > ~110 natural usage -> no spills; grid 1536 gives the waves.
__global__ __launch_bounds__(256, 4) void attn_splitk_kernel(_Float16* __restrict__ ws) {
    attn_body<2>(ws);
}

// ---------------- split-K combine: merge 2 partials -> ctx fp16 ----------------
__global__ __launch_bounds__(256) void combine_kernel(_Float16* __restrict__ ws) {
    const _Float16* __restrict__ op = ws + OFF_OP;
    const float* __restrict__ ml = (const float*)((const char*)ws + OFF_ML_BYTES);
    _Float16* __restrict__ ctx = ws + OFF_CTX;

    int g = blockIdx.x * 256 + threadIdx.x;     // 393216 threads
    int row = g >> 3, chunk = g & 7;            // row in [0, 49152)
    int bh = row >> 10, q = row & 1023;
    int b_ = bh / NHEAD, h = bh % NHEAD;

    float m0 = ml[(size_t)row * 2], l0 = ml[(size_t)row * 2 + 1];
    float m1 = ml[(size_t)(49152 + row) * 2], l1 = ml[(size_t)(49152 + row) * 2 + 1];
    float M = fmaxf(m0, m1);
    float w0 = __builtin_amdgcn_exp2f((m0 - M) * LOG2E);
    float w1 = __builtin_amdgcn_exp2f((m1 - M) * LOG2E);
    float inv_l = 1.0f / (w0 * l0 + w1 * l1);

    half8 o0 = *(const half8*)(op + (size_t)row * 64 + chunk * 8);
    half8 o1 = *(const half8*)(op + (size_t)(49152 + row) * 64 + chunk * 8);
    half8 o;
#pragma unroll
    for (int j = 0; j < 8; j++)
        o[j] = (_Float16)(((float)o0[j] * w0 + (float)o1[j] * w1) * inv_l);
    *(half8*)(ctx + ((size_t)(b_ * TSEQ + q)) * DM + h * DHEAD + chunk * 8) = o;
}

// ---------------- output projection, m97-style: out = ctx @ Wo^T + bo (fp32) ----------------
__global__ __launch_bounds__(256) void proj_kernel(const _Float16* __restrict__ ws,
                                                   const float* __restrict__ bo,
                                                   float* __restrict__ out) {
    __shared__ __align__(16) _Float16 ldsA[128 * 32];
    __shared__ __align__(16) _Float16 ldsB[128 * 32];

    const _Float16* __restrict__ gA = ws + OFF_CTX + (size_t)blockIdx.x * 128 * DM;
    const _Float16* __restrict__ gB = ws + OFF_WOH + (size_t)blockIdx.y * 128 * DM;

    const int tid  = threadIdx.x;
    const int lane = tid & 63;
    const int wid  = tid >> 6;
    const int quad = lane >> 4, l15 = lane & 15;
    const int wm = (wid & 1) * 64, wn = (wid >> 1) * 64;

    const int srow = (lane >> 2);
    const int scol = (lane & 3) * 8;
    const size_t goff0 = (size_t)(wid * 32 + srow) * DM + scol;
    const size_t goff1 = (size_t)(wid * 32 + 16 + srow) * DM + scol;
    _Float16* lA0 = ldsA + wid * 1024;
    _Float16* lA1 = ldsA + wid * 1024 + 512;
    _Float16* lB0 = ldsB + wid * 1024;
    _Float16* lB1 = ldsB + wid * 1024 + 512;

    f32x4 acc[4][4] = {};
    for (int k0 = 0; k0 < DM; k0 += 32) {
        gload16(gA + goff0 + k0, lA0);
        gload16(gA + goff1 + k0, lA1);
        gload16(gB + goff0 + k0, lB0);
        gload16(gB + goff1 + k0, lB1);
        __syncthreads();

        half8 a[4], b[4];
#pragma unroll
        for (int t = 0; t < 4; t++) {
            a[t] = *(const half8*)(ldsA + (wm + t * 16 + l15) * 32 + quad * 8);
            b[t] = *(const half8*)(ldsB + (wn + t * 16 + l15) * 32 + quad * 8);
        }
#pragma unroll
        for (int mt = 0; mt < 4; mt++)
#pragma unroll
            for (int nt = 0; nt < 4; nt++)
                acc[mt][nt] = __builtin_amdgcn_mfma_f32_16x16x32_f16(a[mt], b[nt], acc[mt][nt], 0, 0, 0);
        __syncthreads();
    }

    const int mb = blockIdx.x * 128, nb = blockIdx.y * 128;
#pragma unroll
    for (int mt = 0; mt < 4; mt++)
#pragma unroll
        for (int nt = 0; nt < 4; nt++)
#pragma unroll
            for (int r = 0; r < 4; r++) {
                int m = mb + wm + mt * 16 + quad * 4 + r;
                int n = nb + wn + nt * 16 + l15;
                out[(size_t)m * DM + n] = acc[mt][nt][r] + bo[n];
            }
}

extern "C" void kernel_launch(void* const* d_in, const int* in_sizes, int n_in,
                              void* d_out, int out_size, void* d_ws, size_t ws_size,
                              hipStream_t stream) {
    const float* x  = (const float*)d_in[0];
    const float* wq = (const float*)d_in[1];
    const float* wk = (const float*)d_in[2];
    const float* wv = (const float*)d_in[3];
    const float* wo = (const float*)d_in[4];
    const float* bo = (const float*)d_in[5];
    _Float16* ws = (_Float16*)d_ws;
    float* out = (float*)d_out;

    cvt_kernel<<<dim3(1536, 5, 1), 256, 0, stream>>>(x, wq, wk, wv, wo, ws);
    qkv_kernel<<<dim3(32, 6, 3), 256, 0, stream>>>(ws);
    if (ws_size >= WS_NEED_SPLITK) {
        attn_splitk_kernel<<<dim3(16, 48, 2), 256, 0, stream>>>(ws);
        combine_kernel<<<dim3(1536, 1, 1), 256, 0, stream>>>(ws);
    } else {
        attn_kernel<<<dim3(16, 48, 1), 256, 0, stream>>>(ws);
    }
    proj_kernel<<<dim3(32, 6, 1), 256, 0, stream>>>(ws, bo, out);
}

// Round 8
// 147.809 us; speedup vs baseline: 1.4542x; 1.0974x over previous
//
#include <hip/hip_runtime.h>

typedef _Float16 half8 __attribute__((ext_vector_type(8)));
typedef float f32x4 __attribute__((ext_vector_type(4)));
typedef unsigned short u16;

#define NHEAD 12
#define DHEAD 64
#define DM    768
#define TSEQ  1024
#define LOG2E 1.44269504f

// ws layout (fp16 elements unless noted). ctx aliases xh (xh dead after qkv).
static constexpr size_t OFF_XH  = 0;         // [4096][768]
static constexpr size_t OFF_WQH = 3145728;   // [768][768]
static constexpr size_t OFF_WKH = 3735552;
static constexpr size_t OFF_WVH = 4325376;
static constexpr size_t OFF_WOH = 4915200;
static constexpr size_t OFF_Q   = 5505024;   // [48][1024][64]
static constexpr size_t OFF_K   = 8650752;   // [48][1024][64]
static constexpr size_t OFF_VT  = 11796480;  // [48][64][1024]
static constexpr size_t OFF_CTX = 0;         // [4096][768], aliases XH
// split-K extras:
static constexpr size_t OFF_OP  = 14942208;  // O partials [2][48*1024][64] fp16
static constexpr size_t OFF_ML_BYTES = 42467328;  // [2][48*1024][2] f32
static constexpr size_t WS_NEED_SPLITK = 43253760; // bytes

typedef const __attribute__((address_space(1))) void* gas_ptr;
typedef __attribute__((address_space(3))) void* las_ptr;
__device__ __forceinline__ void gload16(const _Float16* g, _Float16* l) {
    __builtin_amdgcn_global_load_lds((gas_ptr)g, (las_ptr)l, 16, 0, 0);
}

// ---- DPP 16-lane row reductions (VALU pipe; replaces ds_bpermute shuffles) ----
// row_ror:N ctrl = 0x120|N; rotations 1,2,4,8 give all-lanes row reduction.
template <int CTRL>
__device__ __forceinline__ float dpp_rotf(float x) {
    int r = __builtin_amdgcn_update_dpp(0, __builtin_bit_cast(int, x), CTRL, 0xF, 0xF, true);
    return __builtin_bit_cast(float, r);
}
__device__ __forceinline__ float row16_max(float x) {
    x = fmaxf(x, dpp_rotf<0x121>(x));
    x = fmaxf(x, dpp_rotf<0x122>(x));
    x = fmaxf(x, dpp_rotf<0x124>(x));
    x = fmaxf(x, dpp_rotf<0x128>(x));
    return x;
}
__device__ __forceinline__ float row16_add(float x) {
    x = x + dpp_rotf<0x121>(x);
    x = x + dpp_rotf<0x122>(x);
    x = x + dpp_rotf<0x124>(x);
    x = x + dpp_rotf<0x128>(x);
    return x;
}

// ---------------- fp32 -> fp16 conversion of x + 4 weights ----------------
__global__ void cvt_kernel(const float* __restrict__ x, const float* __restrict__ wq,
                           const float* __restrict__ wk, const float* __restrict__ wv,
                           const float* __restrict__ wo, _Float16* __restrict__ ws) {
    int seg = blockIdx.y;
    const float* src;
    _Float16* dst;
    int n;
    if (seg == 0)      { src = x;  dst = ws + OFF_XH;  n = 3145728; }
    else if (seg == 1) { src = wq; dst = ws + OFF_WQH; n = 589824; }
    else if (seg == 2) { src = wk; dst = ws + OFF_WKH; n = 589824; }
    else if (seg == 3) { src = wv; dst = ws + OFF_WVH; n = 589824; }
    else               { src = wo; dst = ws + OFF_WOH; n = 589824; }
    int i = (blockIdx.x * blockDim.x + threadIdx.x) * 8;
    if (i < n) {
        float4 v0 = *(const float4*)(src + i);
        float4 v1 = *(const float4*)(src + i + 4);
        half8 o;
        o[0] = (_Float16)v0.x; o[1] = (_Float16)v0.y;
        o[2] = (_Float16)v0.z; o[3] = (_Float16)v0.w;
        o[4] = (_Float16)v1.x; o[5] = (_Float16)v1.y;
        o[6] = (_Float16)v1.z; o[7] = (_Float16)v1.w;
        *(half8*)(dst + i) = o;
    }
}

// ---------------- QKV GEMM, m97-style LDS-staged ----------------
__global__ __launch_bounds__(256) void qkv_kernel(_Float16* __restrict__ ws) {
    __shared__ __align__(16) _Float16 ldsA[128 * 32];
    __shared__ __align__(16) _Float16 ldsB[128 * 32];

    const int z = blockIdx.z;
    const _Float16* __restrict__ xh = ws + OFF_XH;
    const _Float16* __restrict__ w  = ws + (z == 0 ? OFF_WQH : z == 1 ? OFF_WKH : OFF_WVH);
    _Float16* __restrict__ outp     = ws + (z == 0 ? OFF_Q   : z == 1 ? OFF_K   : OFF_VT);

    const int tid  = threadIdx.x;
    const int lane = tid & 63;
    const int wid  = tid >> 6;
    const int quad = lane >> 4, l15 = lane & 15;
    const int wm = (wid & 1) * 64, wn = (wid >> 1) * 64;

    int mb, nb;
    const _Float16 *gA, *gB;
    if (z < 2) {
        mb = blockIdx.x * 128;              // tokens
        nb = blockIdx.y * 128;              // features
        gA = xh + (size_t)mb * DM;
        gB = w  + (size_t)nb * DM;
    } else {
        mb = blockIdx.y * 128;              // features
        nb = blockIdx.x * 128;              // tokens
        gA = w  + (size_t)mb * DM;
        gB = xh + (size_t)nb * DM;
    }

    const int srow = (lane >> 2);
    const int scol = (lane & 3) * 8;
    const size_t goff0 = (size_t)(wid * 32 + srow) * DM + scol;
    const size_t goff1 = (size_t)(wid * 32 + 16 + srow) * DM + scol;
    _Float16* lA0 = ldsA + wid * 1024;
    _Float16* lA1 = ldsA + wid * 1024 + 512;
    _Float16* lB0 = ldsB + wid * 1024;
    _Float16* lB1 = ldsB + wid * 1024 + 512;

    f32x4 acc[4][4] = {};
    for (int k0 = 0; k0 < DM; k0 += 32) {
        gload16(gA + goff0 + k0, lA0);
        gload16(gA + goff1 + k0, lA1);
        gload16(gB + goff0 + k0, lB0);
        gload16(gB + goff1 + k0, lB1);
        __syncthreads();

        half8 a[4], b[4];
#pragma unroll
        for (int t = 0; t < 4; t++) {
            a[t] = *(const half8*)(ldsA + (wm + t * 16 + l15) * 32 + quad * 8);
            b[t] = *(const half8*)(ldsB + (wn + t * 16 + l15) * 32 + quad * 8);
        }
#pragma unroll
        for (int mt = 0; mt < 4; mt++)
#pragma unroll
            for (int nt = 0; nt < 4; nt++)
                acc[mt][nt] = __builtin_amdgcn_mfma_f32_16x16x32_f16(a[mt], b[nt], acc[mt][nt], 0, 0, 0);
        __syncthreads();
    }

#pragma unroll
    for (int mt = 0; mt < 4; mt++)
#pragma unroll
        for (int nt = 0; nt < 4; nt++)
#pragma unroll
            for (int r = 0; r < 4; r++) {
                int m = mb + wm + mt * 16 + quad * 4 + r;
                int n = nb + wn + nt * 16 + l15;
                size_t idx;
                if (z < 2) {
                    int bb = m >> 10, tt = m & 1023;
                    int h = n >> 6, d = n & 63;
                    idx = ((size_t)(bb * NHEAD + h) * TSEQ + tt) * DHEAD + d;
                } else {
                    int h = m >> 6, d = m & 63;
                    int bb = n >> 10, tt = n & 1023;
                    idx = ((size_t)(bb * NHEAD + h) * DHEAD + d) * TSEQ + tt;
                }
                outp[idx] = (_Float16)acc[mt][nt][r];
            }
}

// ---------------- flash attention core (templated over split) ----------------
// grid (16, 48, NZ); block 256 = 4 waves; wave q-tile 16; key tiles of 64.
template <int NZ>
__device__ __forceinline__ void attn_body(_Float16* __restrict__ ws) {
    __shared__ __align__(16) _Float16 ldsK[64 * 64];
    __shared__ __align__(16) _Float16 ldsV[64 * 64];
    __shared__ __align__(16) _Float16 ldsP[4][16 * 72];

    const int tid  = threadIdx.x;
    const int lane = tid & 63;
    const int wid  = tid >> 6;
    const int quad = lane >> 4, l15 = lane & 15;
    const int bh = blockIdx.y;
    const int z  = (NZ > 1) ? blockIdx.z : 0;
    const int q0 = blockIdx.x * 64 + wid * 16;
    const int kbeg = z * (TSEQ / NZ), kend = kbeg + TSEQ / NZ;

    const _Float16* __restrict__ Q  = ws + OFF_Q  + (size_t)bh * TSEQ * DHEAD;
    const _Float16* __restrict__ K  = ws + OFF_K  + (size_t)bh * TSEQ * DHEAD;
    const _Float16* __restrict__ VT = ws + OFF_VT + (size_t)bh * DHEAD * TSEQ;
    _Float16* pbase = ldsP[wid];

    const int srow0 = tid >> 3, sc0 = tid & 7;
    const int ldsOff0 = srow0 * 64 + ((sc0 ^ (srow0 & 7)) * 8);
    const int ldsOff1 = (srow0 + 32) * 64 + ((sc0 ^ (srow0 & 7)) * 8);

    half8 qf[2];
#pragma unroll
    for (int ks = 0; ks < 2; ks++) {
        qf[ks] = *(const half8*)(Q + (size_t)(q0 + l15) * DHEAD + ks * 32 + quad * 8);
        qf[ks] = qf[ks] * (_Float16)0.125f;   // fold 1/sqrt(64) into Q
    }

    float mrun[4], lrun[4];
    f32x4 oacc[4] = {};
#pragma unroll
    for (int r = 0; r < 4; r++) { mrun[r] = -1e30f; lrun[r] = 0.f; }

    uint4 ka, kb, va, vb;
    ka = *(const uint4*)(K + kbeg * DHEAD + tid * 8);
    kb = *(const uint4*)(K + kbeg * DHEAD + 2048 + tid * 8);
    va = *(const uint4*)(VT + (size_t)srow0 * TSEQ + kbeg + sc0 * 8);
    vb = *(const uint4*)(VT + (size_t)(srow0 + 32) * TSEQ + kbeg + sc0 * 8);

    for (int kt = kbeg; kt < kend; kt += 64) {
        *(uint4*)(ldsK + ldsOff0) = ka;
        *(uint4*)(ldsK + ldsOff1) = kb;
        *(uint4*)(ldsV + ldsOff0) = va;
        *(uint4*)(ldsV + ldsOff1) = vb;
        __syncthreads();

        if (kt + 64 < kend) {
            ka = *(const uint4*)(K + (kt + 64) * DHEAD + tid * 8);
            kb = *(const uint4*)(K + (kt + 64) * DHEAD + 2048 + tid * 8);
            va = *(const uint4*)(VT + (size_t)srow0 * TSEQ + kt + 64 + sc0 * 8);
            vb = *(const uint4*)(VT + (size_t)(srow0 + 32) * TSEQ + kt + 64 + sc0 * 8);
        }

        half8 kf[4][2];
#pragma unroll
        for (int n = 0; n < 4; n++)
#pragma unroll
            for (int ks = 0; ks < 2; ks++) {
                int row = n * 16 + l15;
                int phys = (ks * 4 + quad) ^ (row & 7);
                kf[n][ks] = *(const half8*)(ldsK + row * 64 + phys * 8);
            }

        f32x4 s[4] = {};
#pragma unroll
        for (int n = 0; n < 4; n++)
#pragma unroll
            for (int ks = 0; ks < 2; ks++)
                s[n] = __builtin_amdgcn_mfma_f32_16x16x32_f16(qf[ks], kf[n][ks], s[n], 0, 0, 0);

        // online softmax, rows = quad*4 + r; reductions over l15 via DPP (VALU)
#pragma unroll
        for (int r = 0; r < 4; r++) {
            float tm = fmaxf(fmaxf(s[0][r], s[1][r]), fmaxf(s[2][r], s[3][r]));
            tm = row16_max(tm);
            float mnew = fmaxf(mrun[r], tm);
            float alpha = __builtin_amdgcn_exp2f((mrun[r] - mnew) * LOG2E);
            mrun[r] = mnew;
            float mL = mnew * LOG2E;
            float ts = 0.f;
#pragma unroll
            for (int n = 0; n < 4; n++) {
                float e = __builtin_amdgcn_exp2f(__builtin_fmaf(s[n][r], LOG2E, -mL));
                s[n][r] = e;
                ts += e;
            }
            ts = row16_add(ts);
            lrun[r] = __builtin_fmaf(lrun[r], alpha, ts);
#pragma unroll
            for (int dn = 0; dn < 4; dn++) oacc[dn][r] *= alpha;
        }

#pragma unroll
        for (int n = 0; n < 4; n++)
#pragma unroll
            for (int r = 0; r < 4; r++)
                pbase[(quad * 4 + r) * 72 + n * 16 + l15] = (_Float16)s[n][r];

        half8 vf[4][2];
#pragma unroll
        for (int dn = 0; dn < 4; dn++)
#pragma unroll
            for (int ks = 0; ks < 2; ks++) {
                int row = dn * 16 + l15;
                int phys = (ks * 4 + quad) ^ (row & 7);
                vf[dn][ks] = *(const half8*)(ldsV + row * 64 + phys * 8);
            }

        half8 pf[2];
#pragma unroll
        for (int ks = 0; ks < 2; ks++)
            pf[ks] = *(const half8*)(pbase + l15 * 72 + ks * 32 + quad * 8);

#pragma unroll
        for (int dn = 0; dn < 4; dn++)
#pragma unroll
            for (int ks = 0; ks < 2; ks++)
                oacc[dn] = __builtin_amdgcn_mfma_f32_16x16x32_f16(pf[ks], vf[dn][ks], oacc[dn], 0, 0, 0);

        __syncthreads();
    }

    if (NZ == 1) {
        _Float16* __restrict__ ctx = ws + OFF_CTX;
        const int b_ = bh / NHEAD, h = bh % NHEAD;
#pragma unroll
        for (int dn = 0; dn < 4; dn++)
#pragma unroll
            for (int r = 0; r < 4; r++) {
                int t_ = q0 + quad * 4 + r;
                int col = h * DHEAD + dn * 16 + l15;
                float v = oacc[dn][r] / lrun[r];
                ctx[((size_t)(b_ * TSEQ + t_)) * DM + col] = (_Float16)v;
            }
    } else {
        _Float16* __restrict__ op = ws + OFF_OP;
        float* __restrict__ ml = (float*)((char*)ws + OFF_ML_BYTES);
        const size_t rowbase = (size_t)z * 48 * TSEQ + (size_t)bh * TSEQ + q0;
#pragma unroll
        for (int dn = 0; dn < 4; dn++)
#pragma unroll
            for (int r = 0; r < 4; r++) {
                size_t row = rowbase + quad * 4 + r;
                op[row * 64 + dn * 16 + l15] = (_Float16)oacc[dn][r];
            }
        if (l15 == 0) {
#pragma unroll
            for (int r = 0; r < 4; r++) {
                size_t row = rowbase + quad * 4 + r;
                ml[row * 2]     = mrun[r];
                ml[row * 2 + 1] = lrun[r];
            }
        }
    }
}

__global__ __launch_bounds__(256, 3) void attn_kernel(_Float16* __restrict__ ws) {
    attn_body<1>(ws);
}
__global__ __launch_bounds__(256, 4) void attn_splitk_kernel(_Float16* __restrict__ ws) {
    attn_body<2>(ws);
}

// ---------------- split-K combine: merge 2 partials -> ctx fp16 ----------------
__global__ __launch_bounds__(256) void combine_kernel(_Float16* __restrict__ ws) {
    const _Float16* __restrict__ op = ws + OFF_OP;
    const float* __restrict__ ml = (const float*)((const char*)ws + OFF_ML_BYTES);
    _Float16* __restrict__ ctx = ws + OFF_CTX;

    int g = blockIdx.x * 256 + threadIdx.x;     // 393216 threads
    int row = g >> 3, chunk = g & 7;            // row in [0, 49152)
    int bh = row >> 10, q = row & 1023;
    int b_ = bh / NHEAD, h = bh % NHEAD;

    float m0 = ml[(size_t)row * 2], l0 = ml[(size_t)row * 2 + 1];
    float m1 = ml[(size_t)(49152 + row) * 2], l1 = ml[(size_t)(49152 + row) * 2 + 1];
    float M = fmaxf(m0, m1);
    float w0 = __builtin_amdgcn_exp2f((m0 - M) * LOG2E);
    float w1 = __builtin_amdgcn_exp2f((m1 - M) * LOG2E);
    float inv_l = 1.0f / (w0 * l0 + w1 * l1);

    half8 o0 = *(const half8*)(op + (size_t)row * 64 + chunk * 8);
    half8 o1 = *(const half8*)(op + (size_t)(49152 + row) * 64 + chunk * 8);
    half8 o;
#pragma unroll
    for (int j = 0; j < 8; j++)
        o[j] = (_Float16)(((float)o0[j] * w0 + (float)o1[j] * w1) * inv_l);
    *(half8*)(ctx + ((size_t)(b_ * TSEQ + q)) * DM + h * DHEAD + chunk * 8) = o;
}

// ---------------- output projection: 64x64 tiles, grid(64,12)=768 blocks ----------------
// block 256 = 4 waves (2x2 of 32x32 wave-tiles); BK=32; out = ctx @ Wo^T + bo (fp32)
__global__ __launch_bounds__(256) void proj_kernel(const _Float16* __restrict__ ws,
                                                   const float* __restrict__ bo,
                                                   float* __restrict__ out) {
    __shared__ __align__(16) _Float16 ldsA[64 * 32];
    __shared__ __align__(16) _Float16 ldsB[64 * 32];

    const _Float16* __restrict__ gA = ws + OFF_CTX + (size_t)blockIdx.x * 64 * DM;
    const _Float16* __restrict__ gB = ws + OFF_WOH + (size_t)blockIdx.y * 64 * DM;

    const int tid  = threadIdx.x;
    const int lane = tid & 63;
    const int wid  = tid >> 6;
    const int quad = lane >> 4, l15 = lane & 15;
    const int wm = (wid & 1) * 32, wn = (wid >> 1) * 32;

    // staging: 64x32 tile = 4 KB = 256 threads x 16 B; thread t: row=t>>2, col=(t&3)*8.
    // Each wave stages 16 rows = 512 halfs -> wave-uniform LDS base = wid*512
    // (BUG in r7: wid*1024 scattered waves 1-3 out of place / out of bounds).
    const int srow = tid >> 2;
    const int scol = (tid & 3) * 8;
    const size_t goff = (size_t)srow * DM + scol;
    _Float16* lA = ldsA + wid * 512;   // + lane*16B implicit
    _Float16* lB = ldsB + wid * 512;

    f32x4 acc[2][2] = {};
    for (int k0 = 0; k0 < DM; k0 += 32) {
        gload16(gA + goff + k0, lA);
        gload16(gB + goff + k0, lB);
        __syncthreads();

        half8 a[2], b[2];
#pragma unroll
        for (int t = 0; t < 2; t++) {
            a[t] = *(const half8*)(ldsA + (wm + t * 16 + l15) * 32 + quad * 8);
            b[t] = *(const half8*)(ldsB + (wn + t * 16 + l15) * 32 + quad * 8);
        }
#pragma unroll
        for (int mt = 0; mt < 2; mt++)
#pragma unroll
            for (int nt = 0; nt < 2; nt++)
                acc[mt][nt] = __builtin_amdgcn_mfma_f32_16x16x32_f16(a[mt], b[nt], acc[mt][nt], 0, 0, 0);
        __syncthreads();
    }

    const int mb = blockIdx.x * 64, nb = blockIdx.y * 64;
#pragma unroll
    for (int mt = 0; mt < 2; mt++)
#pragma unroll
        for (int nt = 0; nt < 2; nt++)
#pragma unroll
            for (int r = 0; r < 4; r++) {
                int m = mb + wm + mt * 16 + quad * 4 + r;
                int n = nb + wn + nt * 16 + l15;
                out[(size_t)m * DM + n] = acc[mt][nt][r] + bo[n];
            }
}

extern "C" void kernel_launch(void* const* d_in, const int* in_sizes, int n_in,
                              void* d_out, int out_size, void* d_ws, size_t ws_size,
                              hipStream_t stream) {
    const float* x  = (const float*)d_in[0];
    const float* wq = (const float*)d_in[1];
    const float* wk = (const float*)d_in[2];
    const float* wv = (const float*)d_in[3];
    const float* wo = (const float*)d_in[4];
    const float* bo = (const float*)d_in[5];
    _Float16* ws = (_Float16*)d_ws;
    float* out = (float*)d_out;

    cvt_kernel<<<dim3(1536, 5, 1), 256, 0, stream>>>(x, wq, wk, wv, wo, ws);
    qkv_kernel<<<dim3(32, 6, 3), 256, 0, stream>>>(ws);
    if (ws_size >= WS_NEED_SPLITK) {
        attn_splitk_kernel<<<dim3(16, 48, 2), 256, 0, stream>>>(ws);
        combine_kernel<<<dim3(1536, 1, 1), 256, 0, stream>>>(ws);
    } else {
        attn_kernel<<<dim3(16, 48, 1), 256, 0, stream>>>(ws);
    }
    proj_kernel<<<dim3(64, 12, 1), 256, 0, stream>>>(ws, bo, out);
}